// Round 1
// baseline (167.608 us; speedup 1.0000x reference)
//
#include <hip/hip_runtime.h>
#include <hip/hip_bf16.h>

#define N 8192
#define D 128
#define TILE 128
#define PITCH 136  // bf16 elems per LDS row: 128 + 8 pad -> 2-way bank alias (free)

typedef __attribute__((ext_vector_type(8))) short short8;
typedef __attribute__((ext_vector_type(4))) float floatx4;

static __device__ inline float softplus_of(const float* __restrict__ phi) {
    float p = phi[0];
    // stable softplus; for our phi (~0.54) this is just log1p(exp(p))
    return (p > 20.f) ? p : log1pf(__expf(p));
}

static __device__ inline unsigned short f2bf(float f) {
    return __builtin_bit_cast(unsigned short, __float2bfloat16(f));
}

// k1: out = x + var*noise (fp32), and sq[i] = sum_k bf16(x[i,k])^2 (fp32 accum)
// One wave per row: 64 lanes x 2 elements = 128 = D.
__global__ __launch_bounds__(256) void k1_prep(
        const float* __restrict__ x, const float* __restrict__ phi,
        const float* __restrict__ noise, float* __restrict__ out,
        float* __restrict__ sq) {
    int wave = threadIdx.x >> 6;
    int lane = threadIdx.x & 63;
    int row  = blockIdx.x * 4 + wave;
    float var = softplus_of(phi);

    const float* xr = x + (size_t)row * D;
    const float* nr = noise + (size_t)row * D;
    float*       orow = out + (size_t)row * D;

    float2 xv = *(const float2*)(xr + lane * 2);
    float2 nv = *(const float2*)(nr + lane * 2);
    float2 ov;
    ov.x = xv.x + var * nv.x;
    ov.y = xv.y + var * nv.y;
    *(float2*)(orow + lane * 2) = ov;

    // squared norm in the bf16 domain (must match what MFMA sees, so the
    // Gram diagonal cancels: d2_ii = 2*sq_i - 2*dot_ii ~ 0)
    float b0 = (float)__float2bfloat16(xv.x);
    float b1 = (float)__float2bfloat16(xv.y);
    float s = b0 * b0 + b1 * b1;
    #pragma unroll
    for (int m = 1; m < 64; m <<= 1) s += __shfl_xor(s, m, 64);
    if (lane == 0) sq[row] = s;
}

// k2: Gram tile (128x128) via mfma_f32_16x16x32_bf16, fused exp epilogue,
// row-sum reduced within wave quads, atomicAdd into rowsum[N].
__global__ __launch_bounds__(256, 2) void k2_gram(
        const float* __restrict__ x, const float* __restrict__ phi,
        const float* __restrict__ sq, float* __restrict__ rowsum) {
    __shared__ __align__(16) unsigned short As[TILE * PITCH];
    __shared__ __align__(16) unsigned short Bs[TILE * PITCH];

    const int ib = blockIdx.x, jb = blockIdx.y;
    const int iBase = ib * TILE, jBase = jb * TILE;
    const int t = threadIdx.x;

    float var = softplus_of(phi);
    float ninvvar = -0.5f / var;

    // stage both tiles: fp32 global -> bf16 LDS, 16B-coalesced loads
    #pragma unroll
    for (int s = 0; s < 16; s++) {
        int chunk = t + 256 * s;          // 0..4095
        int r = chunk >> 5;               // 0..127
        int c = (chunk & 31) * 4;         // 0..124
        float4 av = *(const float4*)(x + (size_t)(iBase + r) * D + c);
        float4 bv = *(const float4*)(x + (size_t)(jBase + r) * D + c);
        ushort4 a4, b4;
        a4.x = f2bf(av.x); a4.y = f2bf(av.y); a4.z = f2bf(av.z); a4.w = f2bf(av.w);
        b4.x = f2bf(bv.x); b4.y = f2bf(bv.y); b4.z = f2bf(bv.z); b4.w = f2bf(bv.w);
        *(ushort4*)&As[r * PITCH + c] = a4;
        *(ushort4*)&Bs[r * PITCH + c] = b4;
    }
    __syncthreads();

    const int wave = t >> 6;
    const int lane = t & 63;
    const int wr = (wave & 1) * 64;   // wave's row quadrant
    const int wc = (wave >> 1) * 64;  // wave's col quadrant
    const int lrow = lane & 15;       // m (A) / n (B) index within 16-tile
    const int quad = lane >> 4;       // k-group

    floatx4 acc[4][4] = {};
    #pragma unroll
    for (int kk = 0; kk < 4; kk++) {
        int koff = kk * 32 + quad * 8;
        short8 af[4], bfr[4];
        #pragma unroll
        for (int mt = 0; mt < 4; mt++)
            af[mt] = *(const short8*)&As[(wr + mt * 16 + lrow) * PITCH + koff];
        #pragma unroll
        for (int nt = 0; nt < 4; nt++)
            bfr[nt] = *(const short8*)&Bs[(wc + nt * 16 + lrow) * PITCH + koff];
        #pragma unroll
        for (int mt = 0; mt < 4; mt++)
            #pragma unroll
            for (int nt = 0; nt < 4; nt++)
                acc[mt][nt] = __builtin_amdgcn_mfma_f32_16x16x32_bf16(
                    af[mt], bfr[nt], acc[mt][nt], 0, 0, 0);
    }

    // epilogue: d2 = max(sq_i + sq_j - 2g, 0); p = exp(-0.5*d2/var); row-sum.
    // C/D layout: col = lane&15, row = quad*4 + reg   [learn_hip m89]
    float sqj[4];
    #pragma unroll
    for (int nt = 0; nt < 4; nt++) sqj[nt] = sq[jBase + wc + nt * 16 + lrow];

    #pragma unroll
    for (int mt = 0; mt < 4; mt++) {
        #pragma unroll
        for (int reg = 0; reg < 4; reg++) {
            int i = iBase + wr + mt * 16 + quad * 4 + reg;
            float si = sq[i];
            float sum = 0.f;
            #pragma unroll
            for (int nt = 0; nt < 4; nt++) {
                float g = acc[mt][nt][reg];
                float d2 = fmaxf(si + sqj[nt] - 2.f * g, 0.f);
                sum += __expf(d2 * ninvvar);
            }
            // reduce across the 16 lanes of the quad (same row, 16 cols x 4 nt)
            #pragma unroll
            for (int m = 1; m < 16; m <<= 1) sum += __shfl_xor(sum, m, 64);
            if (lrow == 0) atomicAdd(&rowsum[i], sum);
        }
    }
}

// k3: IXT = (ln N - mean_i ln rowsum[i]) / ln 2, single block
__global__ __launch_bounds__(1024) void k3_final(
        const float* __restrict__ rowsum, float* __restrict__ out_ixt) {
    __shared__ float red[16];
    int t = threadIdx.x;
    float local = 0.f;
    for (int i = t; i < N; i += 1024) local += logf(rowsum[i]);
    #pragma unroll
    for (int m = 1; m < 64; m <<= 1) local += __shfl_xor(local, m, 64);
    if ((t & 63) == 0) red[t >> 6] = local;
    __syncthreads();
    if (t < 16) {
        float v = red[t];
        #pragma unroll
        for (int m = 1; m < 16; m <<= 1) v += __shfl_xor(v, m, 64);
        if (t == 0) {
            float kde = v / (float)N;
            out_ixt[0] = (logf((float)N) - kde) * 1.4426950408889634f;
        }
    }
}

extern "C" void kernel_launch(void* const* d_in, const int* in_sizes, int n_in,
                              void* d_out, int out_size, void* d_ws, size_t ws_size,
                              hipStream_t stream) {
    const float* x     = (const float*)d_in[0];
    const float* phi   = (const float*)d_in[1];
    const float* noise = (const float*)d_in[2];
    float* out = (float*)d_out;

    float* rowsum = (float*)d_ws;       // N floats, atomic-accumulated
    float* sq     = rowsum + N;         // N floats

    hipMemsetAsync(rowsum, 0, N * sizeof(float), stream);
    k1_prep<<<N / 4, 256, 0, stream>>>(x, phi, noise, out, sq);
    dim3 g2(N / TILE, N / TILE);
    k2_gram<<<g2, 256, 0, stream>>>(x, phi, sq, rowsum);
    k3_final<<<1, 1024, 0, stream>>>(rowsum, out + (size_t)N * D);
}

// Round 2
// 162.762 us; speedup vs baseline: 1.0298x; 1.0298x over previous
//
#include <hip/hip_runtime.h>
#include <hip/hip_bf16.h>

#define N 8192
#define D 128
#define TILE 128
#define JCHUNK 8
#define PITCH 136  // bf16 elems per LDS row: 128 + 8 pad (16B-aligned rows, <=2-way bank alias)

typedef __attribute__((ext_vector_type(8))) short short8;
typedef __attribute__((ext_vector_type(4))) float floatx4;

static __device__ inline float softplus_of(const float* __restrict__ phi) {
    float p = phi[0];
    return (p > 20.f) ? p : log1pf(__expf(p));
}

static __device__ inline unsigned short f2bf(float f) {
    return __builtin_bit_cast(unsigned short, __float2bfloat16(f));
}

// pack 8 fp32 -> 8 bf16 (RNE, matches __float2bfloat16)
static __device__ inline short8 pack8(float4 a, float4 b) {
    short8 r;
    r[0] = (short)f2bf(a.x); r[1] = (short)f2bf(a.y);
    r[2] = (short)f2bf(a.z); r[3] = (short)f2bf(a.w);
    r[4] = (short)f2bf(b.x); r[5] = (short)f2bf(b.y);
    r[6] = (short)f2bf(b.z); r[7] = (short)f2bf(b.w);
    return r;
}

// k1: out = x + var*noise; sq[i] = ||bf16(x_i)||^2 (bf16 domain so Gram diag cancels);
// also zero-inits rowsum (saves a memset launch). One wave per row.
__global__ __launch_bounds__(256) void k1_prep(
        const float* __restrict__ x, const float* __restrict__ phi,
        const float* __restrict__ noise, float* __restrict__ out,
        float* __restrict__ sq, float* __restrict__ rowsum) {
    int wave = threadIdx.x >> 6;
    int lane = threadIdx.x & 63;
    int row  = blockIdx.x * 4 + wave;
    float var = softplus_of(phi);

    const float* xr = x + (size_t)row * D;
    const float* nr = noise + (size_t)row * D;
    float*       orow = out + (size_t)row * D;

    float2 xv = *(const float2*)(xr + lane * 2);
    float2 nv = *(const float2*)(nr + lane * 2);
    float2 ov;
    ov.x = xv.x + var * nv.x;
    ov.y = xv.y + var * nv.y;
    *(float2*)(orow + lane * 2) = ov;

    float b0 = (float)__float2bfloat16(xv.x);
    float b1 = (float)__float2bfloat16(xv.y);
    float s = b0 * b0 + b1 * b1;
    #pragma unroll
    for (int m = 1; m < 64; m <<= 1) s += __shfl_xor(s, m, 64);
    if (lane == 0) { sq[row] = s; rowsum[row] = 0.f; }
}

// k2: per block: A-frags in registers (loaded once), loop over JCHUNK B-tiles
// with double-buffered LDS; fused exp epilogue accumulates row-sums in
// registers; one shuffle-reduce + atomicAdd per row at the end.
__global__ __launch_bounds__(256, 2) void k2_gram(
        const float* __restrict__ x, const float* __restrict__ phi,
        const float* __restrict__ sq, float* __restrict__ rowsum) {
    __shared__ __align__(16) unsigned short Bs[2][TILE * PITCH];

    const int t = threadIdx.x;
    const int wave = t >> 6;
    const int lane = t & 63;
    const int lrow = lane & 15;
    const int quad = lane >> 4;
    const int wr = (wave & 1) * 64;   // wave row quadrant
    const int wc = (wave >> 1) * 64;  // wave col quadrant
    const int iBase  = blockIdx.x * TILE;
    const int jBase0 = blockIdx.y * (JCHUNK * TILE);

    float var = softplus_of(phi);
    float ninvvar = -0.5f / var;

    // ---- A fragments straight from global (L2-hot; read by only 8 blocks) ----
    short8 af[4][4];
    #pragma unroll
    for (int mt = 0; mt < 4; mt++) {
        const float* rowp = x + (size_t)(iBase + wr + mt * 16 + lrow) * D + quad * 8;
        #pragma unroll
        for (int kk = 0; kk < 4; kk++) {
            float4 u = *(const float4*)(rowp + kk * 32);
            float4 v = *(const float4*)(rowp + kk * 32 + 4);
            af[mt][kk] = pack8(u, v);
        }
    }
    float si[4][4];
    #pragma unroll
    for (int mt = 0; mt < 4; mt++)
        #pragma unroll
        for (int reg = 0; reg < 4; reg++)
            si[mt][reg] = sq[iBase + wr + mt * 16 + quad * 4 + reg];

    float rowAcc[4][4] = {};

    // ---- stage B tile 0 ----
    {
        const float* src = x + (size_t)jBase0 * D;
        #pragma unroll
        for (int s = 0; s < 8; s++) {
            int chunk = t + 256 * s;      // 0..2047
            int r = chunk >> 4;           // 0..127
            int c = (chunk & 15) * 8;     // 0..120
            float4 u = *(const float4*)(src + (size_t)r * D + c);
            float4 v = *(const float4*)(src + (size_t)r * D + c + 4);
            *(short8*)&Bs[0][r * PITCH + c] = pack8(u, v);
        }
    }
    __syncthreads();

    for (int jt = 0; jt < JCHUNK; ++jt) {
        const int jBase = jBase0 + jt * TILE;

        // issue next tile's global loads BEFORE compute (stay in flight)
        float4 ld[16];
        if (jt + 1 < JCHUNK) {
            const float* src = x + (size_t)(jBase + TILE) * D;
            #pragma unroll
            for (int s = 0; s < 8; s++) {
                int chunk = t + 256 * s;
                int r = chunk >> 4;
                int c = (chunk & 15) * 8;
                ld[2 * s]     = *(const float4*)(src + (size_t)r * D + c);
                ld[2 * s + 1] = *(const float4*)(src + (size_t)r * D + c + 4);
            }
        }

        // ---- MFMA on current buffer ----
        const unsigned short* B = Bs[jt & 1];
        floatx4 acc[4][4] = {};
        #pragma unroll
        for (int kk = 0; kk < 4; kk++) {
            int koff = kk * 32 + quad * 8;
            short8 bfr[4];
            #pragma unroll
            for (int nt = 0; nt < 4; nt++)
                bfr[nt] = *(const short8*)&B[(wc + nt * 16 + lrow) * PITCH + koff];
            #pragma unroll
            for (int mt = 0; mt < 4; mt++)
                #pragma unroll
                for (int nt = 0; nt < 4; nt++)
                    acc[mt][nt] = __builtin_amdgcn_mfma_f32_16x16x32_bf16(
                        af[mt][kk], bfr[nt], acc[mt][nt], 0, 0, 0);
        }

        // ---- fused epilogue: accumulate exp into registers ----
        // C/D layout: col = lane&15, row = quad*4 + reg  [learn_hip m89]
        float sqj[4];
        #pragma unroll
        for (int nt = 0; nt < 4; nt++)
            sqj[nt] = sq[jBase + wc + nt * 16 + lrow];
        #pragma unroll
        for (int mt = 0; mt < 4; mt++) {
            #pragma unroll
            for (int reg = 0; reg < 4; reg++) {
                float s0 = si[mt][reg];
                #pragma unroll
                for (int nt = 0; nt < 4; nt++) {
                    float g  = acc[mt][nt][reg];
                    float d2 = fmaxf(fmaf(-2.f, g, s0 + sqj[nt]), 0.f);
                    rowAcc[mt][reg] += __expf(d2 * ninvvar);
                }
            }
        }

        // ---- write prefetched tile into the other buffer ----
        if (jt + 1 < JCHUNK) {
            unsigned short* dst = Bs[(jt + 1) & 1];
            #pragma unroll
            for (int s = 0; s < 8; s++) {
                int chunk = t + 256 * s;
                int r = chunk >> 4;
                int c = (chunk & 15) * 8;
                *(short8*)&dst[r * PITCH + c] = pack8(ld[2 * s], ld[2 * s + 1]);
            }
        }
        __syncthreads();
    }

    // ---- per-row reduce over the 16 lanes of the quad, one atomic per row ----
    #pragma unroll
    for (int mt = 0; mt < 4; mt++) {
        #pragma unroll
        for (int reg = 0; reg < 4; reg++) {
            float v = rowAcc[mt][reg];
            #pragma unroll
            for (int m = 1; m < 16; m <<= 1) v += __shfl_xor(v, m, 64);
            if (lrow == 0)
                atomicAdd(&rowsum[iBase + wr + mt * 16 + quad * 4 + reg], v);
        }
    }
}

// k3: IXT = (ln N - mean_i ln rowsum[i]) / ln 2, single block
__global__ __launch_bounds__(1024) void k3_final(
        const float* __restrict__ rowsum, float* __restrict__ out_ixt) {
    __shared__ float red[16];
    int t = threadIdx.x;
    float local = 0.f;
    for (int i = t; i < N; i += 1024) local += logf(rowsum[i]);
    #pragma unroll
    for (int m = 1; m < 64; m <<= 1) local += __shfl_xor(local, m, 64);
    if ((t & 63) == 0) red[t >> 6] = local;
    __syncthreads();
    if (t < 16) {
        float v = red[t];
        #pragma unroll
        for (int m = 1; m < 16; m <<= 1) v += __shfl_xor(v, m, 64);
        if (t == 0) {
            float kde = v / (float)N;
            out_ixt[0] = (logf((float)N) - kde) * 1.4426950408889634f;
        }
    }
}

extern "C" void kernel_launch(void* const* d_in, const int* in_sizes, int n_in,
                              void* d_out, int out_size, void* d_ws, size_t ws_size,
                              hipStream_t stream) {
    const float* x     = (const float*)d_in[0];
    const float* phi   = (const float*)d_in[1];
    const float* noise = (const float*)d_in[2];
    float* out = (float*)d_out;

    float* rowsum = (float*)d_ws;       // N floats, atomic-accumulated
    float* sq     = rowsum + N;         // N floats

    k1_prep<<<N / 4, 256, 0, stream>>>(x, phi, noise, out, sq, rowsum);
    dim3 g2(N / TILE, N / (TILE * JCHUNK));
    k2_gram<<<g2, 256, 0, stream>>>(x, phi, sq, rowsum);
    k3_final<<<1, 1024, 0, stream>>>(rowsum, out + (size_t)N * D);
}

// Round 3
// 101.440 us; speedup vs baseline: 1.6523x; 1.6045x over previous
//
#include <hip/hip_runtime.h>
#include <hip/hip_bf16.h>

#define N 8192
#define D 128
#define TILE 128
#define JCHUNK 8

typedef __attribute__((ext_vector_type(8))) short short8;
typedef __attribute__((ext_vector_type(4))) float floatx4;
typedef unsigned int u32;

// async global->LDS, 16B per lane; LDS dest = wave-uniform base + lane*16
#define GLOAD_LDS16(g, l) \
    __builtin_amdgcn_global_load_lds((const __attribute__((address_space(1))) u32*)(g), \
                                     (__attribute__((address_space(3))) u32*)(l), 16, 0, 0)

static __device__ inline float softplus_of(const float* __restrict__ phi) {
    float p = phi[0];
    return (p > 20.f) ? p : log1pf(__expf(p));
}

static __device__ inline unsigned short f2bf(float f) {
    return __builtin_bit_cast(unsigned short, __float2bfloat16(f));
}

static __device__ inline short8 pack8(float4 a, float4 b) {
    short8 r;
    r[0] = (short)f2bf(a.x); r[1] = (short)f2bf(a.y);
    r[2] = (short)f2bf(a.z); r[3] = (short)f2bf(a.w);
    r[4] = (short)f2bf(b.x); r[5] = (short)f2bf(b.y);
    r[6] = (short)f2bf(b.z); r[7] = (short)f2bf(b.w);
    return r;
}

// k1: bf16x[r, gc^(r&15) group] = bf16(x[r, gc group])  (XOR-swizzled 16B groups
// so unpadded LDS tiles read conflict-lean); sq[r] = ||bf16(x_r)||^2; rowsum=0.
// One thread per 16B group: 8192 rows * 16 groups / 256 = 512 blocks.
__global__ __launch_bounds__(256) void k1_cvt(
        const float* __restrict__ x, unsigned short* __restrict__ bf16x,
        float* __restrict__ sq, float* __restrict__ rowsum) {
    int gid = blockIdx.x * 256 + threadIdx.x;
    int row = gid >> 4;
    int gc  = gid & 15;
    const float* src = x + (size_t)row * D + gc * 8;
    float4 u = *(const float4*)src;
    float4 v = *(const float4*)(src + 4);
    short8 p = pack8(u, v);
    int gp = gc ^ (row & 15);
    *(short8*)&bf16x[(size_t)row * D + gp * 8] = p;

    float s = 0.f;
    #pragma unroll
    for (int k = 0; k < 8; k++) {
        u32 bits = ((u32)(unsigned short)p[k]) << 16;
        float b = __builtin_bit_cast(float, bits);
        s += b * b;
    }
    // reduce across the 16 lanes of this row (xor masks 1,2,4,8 stay in-group)
    #pragma unroll
    for (int m = 1; m < 16; m <<= 1) s += __shfl_xor(s, m, 64);
    if (gc == 0) { sq[row] = s; rowsum[row] = 0.f; }
}

// k2: 64 i-tiles x 8 j-chunks = 512 blocks (2/CU, one round). A-frags in regs
// (read once from swizzled bf16x), 8 B-tiles double-buffered via
// global_load_lds (zero staging VGPRs). Fused exp epilogue accumulates
// row-sums in registers; one shuffle-reduce + atomic per row per block.
__global__ __launch_bounds__(256, 2) void k2_gram(
        const unsigned short* __restrict__ bf16x, const float* __restrict__ phi,
        const float* __restrict__ sq, float* __restrict__ rowsum) {
    __shared__ __align__(16) unsigned short Bs[2][TILE * D];  // 2 x 32 KB, unpadded

    const int t = threadIdx.x;
    const int wave = t >> 6;
    const int lane = t & 63;
    const int lrow = lane & 15;
    const int quad = lane >> 4;
    const int wr = (wave & 1) * 64;   // wave row quadrant
    const int wc = (wave >> 1) * 64;  // wave col quadrant
    const int iBase  = blockIdx.x * TILE;
    const int jBase0 = blockIdx.y * (JCHUNK * TILE);

    float var = softplus_of(phi);
    float ninvvar = -0.5f / var;

    // ---- A fragments from swizzled global bf16 (L2-hot, read by 8 blocks) ----
    short8 af[4][4];
    #pragma unroll
    for (int mt = 0; mt < 4; mt++) {
        const unsigned short* arow = bf16x + (size_t)(iBase + wr + mt * 16 + lrow) * D;
        #pragma unroll
        for (int kk = 0; kk < 4; kk++)
            af[mt][kk] = *(const short8*)&arow[((kk * 4 + quad) ^ lrow) * 8];
    }
    float si[4][4];
    #pragma unroll
    for (int mt = 0; mt < 4; mt++)
        #pragma unroll
        for (int reg = 0; reg < 4; reg++)
            si[mt][reg] = sq[iBase + wr + mt * 16 + quad * 4 + reg];

    float rowAcc[4][4] = {};

    // ---- stage tile 0 (async DMA) ----
    {
        const unsigned short* src = bf16x + (size_t)jBase0 * D;
        #pragma unroll
        for (int s = 0; s < 8; s++) {
            int cb = s * 256 + wave * 64;            // wave-uniform chunk base
            GLOAD_LDS16(src + (size_t)(cb + lane) * 8, &Bs[0][cb * 8]);
        }
    }
    __syncthreads();

    for (int jt = 0; jt < JCHUNK; ++jt) {
        // issue next tile's DMA into the other buffer; in flight during compute
        if (jt + 1 < JCHUNK) {
            const unsigned short* src = bf16x + (size_t)(jBase0 + (jt + 1) * TILE) * D;
            unsigned short* dstb = Bs[(jt + 1) & 1];
            #pragma unroll
            for (int s = 0; s < 8; s++) {
                int cb = s * 256 + wave * 64;
                GLOAD_LDS16(src + (size_t)(cb + lane) * 8, &dstb[cb * 8]);
            }
        }

        // ---- MFMA on current buffer ----
        const unsigned short* B = Bs[jt & 1];
        floatx4 acc[4][4] = {};
        #pragma unroll
        for (int kk = 0; kk < 4; kk++) {
            short8 bfr[4];
            #pragma unroll
            for (int nt = 0; nt < 4; nt++) {
                int R = wc + nt * 16 + lrow;
                bfr[nt] = *(const short8*)&B[(size_t)R * D + (((kk * 4 + quad) ^ lrow) * 8)];
            }
            #pragma unroll
            for (int mt = 0; mt < 4; mt++)
                #pragma unroll
                for (int nt = 0; nt < 4; nt++)
                    acc[mt][nt] = __builtin_amdgcn_mfma_f32_16x16x32_bf16(
                        af[mt][kk], bfr[nt], acc[mt][nt], 0, 0, 0);
        }

        // ---- fused epilogue: d2 = max(si+sj-2g,0); rowAcc += exp(-d2/2var) ----
        // C/D layout: col = lane&15, row = quad*4 + reg  [learn_hip m89]
        const int jBase = jBase0 + jt * TILE;
        float sqj[4];
        #pragma unroll
        for (int nt = 0; nt < 4; nt++)
            sqj[nt] = sq[jBase + wc + nt * 16 + lrow];
        #pragma unroll
        for (int mt = 0; mt < 4; mt++) {
            #pragma unroll
            for (int reg = 0; reg < 4; reg++) {
                float s0 = si[mt][reg];
                #pragma unroll
                for (int nt = 0; nt < 4; nt++) {
                    float g  = acc[mt][nt][reg];
                    float d2 = fmaxf(fmaf(-2.f, g, s0 + sqj[nt]), 0.f);
                    rowAcc[mt][reg] += __expf(d2 * ninvvar);
                }
            }
        }

        __syncthreads();  // drains DMA (next buffer ready) + guards buffer reuse
    }

    // ---- per-row reduce over the quad's 16 lanes, one atomic per row ----
    #pragma unroll
    for (int mt = 0; mt < 4; mt++) {
        #pragma unroll
        for (int reg = 0; reg < 4; reg++) {
            float v = rowAcc[mt][reg];
            #pragma unroll
            for (int m = 1; m < 16; m <<= 1) v += __shfl_xor(v, m, 64);
            if (lrow == 0)
                atomicAdd(&rowsum[iBase + wr + mt * 16 + quad * 4 + reg], v);
        }
    }
}

// k3: IXT = (ln N - mean_i ln rowsum[i]) / ln 2
__global__ __launch_bounds__(1024) void k3_final(
        const float* __restrict__ rowsum, float* __restrict__ out_ixt) {
    __shared__ float red[16];
    int t = threadIdx.x;
    float local = 0.f;
    for (int i = t; i < N; i += 1024) local += logf(rowsum[i]);
    #pragma unroll
    for (int m = 1; m < 64; m <<= 1) local += __shfl_xor(local, m, 64);
    if ((t & 63) == 0) red[t >> 6] = local;
    __syncthreads();
    if (t < 16) {
        float v = red[t];
        #pragma unroll
        for (int m = 1; m < 16; m <<= 1) v += __shfl_xor(v, m, 64);
        if (t == 0) {
            float kde = v / (float)N;
            out_ixt[0] = (logf((float)N) - kde) * 1.4426950408889634f;
        }
    }
}

// k4: out = x + var*noise (runs LAST — overwrites the bf16 scratch in d_out)
__global__ __launch_bounds__(256) void k4_noise(
        const float4* __restrict__ x, const float* __restrict__ phi,
        const float4* __restrict__ noise, float4* __restrict__ out) {
    int i = blockIdx.x * 256 + threadIdx.x;
    float var = softplus_of(phi);
    float4 xv = x[i], nv = noise[i];
    float4 ov;
    ov.x = xv.x + var * nv.x;
    ov.y = xv.y + var * nv.y;
    ov.z = xv.z + var * nv.z;
    ov.w = xv.w + var * nv.w;
    out[i] = ov;
}

extern "C" void kernel_launch(void* const* d_in, const int* in_sizes, int n_in,
                              void* d_out, int out_size, void* d_ws, size_t ws_size,
                              hipStream_t stream) {
    const float* x     = (const float*)d_in[0];
    const float* phi   = (const float*)d_in[1];
    const float* noise = (const float*)d_in[2];
    float* out = (float*)d_out;

    float* rowsum = (float*)d_ws;                     // N floats
    float* sq     = rowsum + N;                       // N floats
    // bf16 scratch lives in d_out[0 .. N*D/2) floats (2 MB of the 4 MB output
    // buffer); consumed by k2, then overwritten by k4. out[N*D] = IXT.
    unsigned short* bf16x = (unsigned short*)d_out;

    k1_cvt<<<(N * 16) / 256, 256, 0, stream>>>(x, bf16x, sq, rowsum);
    dim3 g2(N / TILE, N / (TILE * JCHUNK));
    k2_gram<<<g2, 256, 0, stream>>>(bf16x, phi, sq, rowsum);
    k3_final<<<1, 1024, 0, stream>>>(rowsum, out + (size_t)N * D);
    k4_noise<<<(N * D / 4) / 256, 256, 0, stream>>>(
        (const float4*)x, phi, (const float4*)noise, (float4*)out);
}

// Round 4
// 97.113 us; speedup vs baseline: 1.7259x; 1.0446x over previous
//
#include <hip/hip_runtime.h>
#include <hip/hip_bf16.h>

#define N 8192
#define D 128
#define TILE 128
#define NT (N / TILE)  // 64 tile-rows; NPAIRS = 64*65/2 = 2080 = 32*5 + 480*4

typedef __attribute__((ext_vector_type(8))) short short8;
typedef __attribute__((ext_vector_type(4))) float floatx4;
typedef unsigned int u32;

// async global->LDS, 16B per lane; LDS dest = wave-uniform base + lane*16
#define GLOAD_LDS16(g, l) \
    __builtin_amdgcn_global_load_lds((const __attribute__((address_space(1))) u32*)(g), \
                                     (__attribute__((address_space(3))) u32*)(l), 16, 0, 0)

static __device__ inline float softplus_of(const float* __restrict__ phi) {
    float p = phi[0];
    return (p > 20.f) ? p : log1pf(__expf(p));
}

static __device__ inline unsigned short f2bf(float f) {
    return __builtin_bit_cast(unsigned short, __float2bfloat16(f));
}

static __device__ inline short8 pack8(float4 a, float4 b) {
    short8 r;
    r[0] = (short)f2bf(a.x); r[1] = (short)f2bf(a.y);
    r[2] = (short)f2bf(a.z); r[3] = (short)f2bf(a.w);
    r[4] = (short)f2bf(b.x); r[5] = (short)f2bf(b.y);
    r[6] = (short)f2bf(b.z); r[7] = (short)f2bf(b.w);
    return r;
}

// k1: bf16x[r, gc^(r&15)] = bf16(x[r, gc])  (XOR-swizzled 16B groups);
// sq[r] = ||bf16(x_r)||^2; rowsum zero-init. One thread per 16B group.
__global__ __launch_bounds__(256) void k1_cvt(
        const float* __restrict__ x, unsigned short* __restrict__ bf16x,
        float* __restrict__ sq, float* __restrict__ rowsum) {
    int gid = blockIdx.x * 256 + threadIdx.x;
    int row = gid >> 4;
    int gc  = gid & 15;
    const float* src = x + (size_t)row * D + gc * 8;
    float4 u = *(const float4*)src;
    float4 v = *(const float4*)(src + 4);
    short8 p = pack8(u, v);
    int gp = gc ^ (row & 15);
    *(short8*)&bf16x[(size_t)row * D + gp * 8] = p;

    float s = 0.f;
    #pragma unroll
    for (int k = 0; k < 8; k++) {
        u32 bits = ((u32)(unsigned short)p[k]) << 16;
        float b = __builtin_bit_cast(float, bits);
        s += b * b;
    }
    #pragma unroll
    for (int m = 1; m < 16; m <<= 1) s += __shfl_xor(s, m, 64);
    if (gc == 0) { sq[row] = s; rowsum[row] = 0.f; }
}

// k2: symmetric Gram. 512 blocks; block b handles 4 (or 5 for b<32)
// consecutive upper-tri tile-pairs (ti<=tj). Per pair: B tile DMA'd
// (double-buffered), A-frags in registers (reloaded on ti change),
// fused exp2 epilogue accumulates ROW sums (-> rows of ti, registers,
// flushed on ti change) and COLUMN sums (-> rows of tj by symmetry,
// flushed per pair; skipped on diagonal pairs).
__global__ __launch_bounds__(256, 2) void k2_gram(
        const unsigned short* __restrict__ bf16x, const float* __restrict__ phi,
        const float* __restrict__ sq, float* __restrict__ rowsum) {
    __shared__ __align__(16) unsigned short Bs[2][TILE * D];  // 2 x 32 KB

    const int t = threadIdx.x;
    const int wave = t >> 6;
    const int lane = t & 63;
    const int lrow = lane & 15;
    const int quad = lane >> 4;
    const int wr = (wave & 1) * 64;
    const int wc = (wave >> 1) * 64;

    const int b = blockIdx.x;
    const int cnt   = (b < 32) ? 5 : 4;
    const int start = (b < 32) ? 5 * b : 160 + 4 * (b - 32);

    // decode start -> (ti, tj) in row-major upper-tri order
    int pti = 0, rem = start, len = NT;
    while (rem >= len) { rem -= len; ++pti; --len; }
    int ptj = pti + rem;

    float var = softplus_of(phi);
    const float e2c = (-0.5f / var) * 1.4426950408889634f;  // fold log2(e)
    const float m2c = -2.0f * e2c;

    // stage pair 0's B tile
    {
        const unsigned short* src = bf16x + (size_t)ptj * TILE * D;
        #pragma unroll
        for (int s = 0; s < 8; s++) {
            int cb = s * 256 + wave * 64;
            GLOAD_LDS16(src + (size_t)(cb + lane) * 8, &Bs[0][cb * 8]);
        }
    }
    __syncthreads();

    short8 af[4][4];
    float sie[4][4];
    float rowAcc[4][4];
    int curTi = -1;

    auto flushRow = [&]() {
        const int iBase = curTi * TILE;
        #pragma unroll
        for (int mt = 0; mt < 4; mt++)
            #pragma unroll
            for (int reg = 0; reg < 4; reg++) {
                float v = rowAcc[mt][reg];
                #pragma unroll
                for (int m = 1; m < 16; m <<= 1) v += __shfl_xor(v, m, 64);
                if (lrow == 0)
                    atomicAdd(&rowsum[iBase + wr + mt * 16 + quad * 4 + reg], v);
            }
    };

    for (int r = 0; r < cnt; ++r) {
        const int jBase = ptj * TILE;

        // sq column loads FIRST (older in vmcnt order than the DMA, so the
        // epilogue's wait on them leaves the prefetch in flight)
        float sje[4];
        #pragma unroll
        for (int nt = 0; nt < 4; nt++)
            sje[nt] = sq[jBase + wc + nt * 16 + lrow] * e2c;

        // next pair + its DMA prefetch into the other buffer
        int nti = pti, ntj = ptj + 1;
        if (ntj == NT) { ++nti; ntj = nti; }
        if (r + 1 < cnt) {
            const unsigned short* src = bf16x + (size_t)ntj * TILE * D;
            unsigned short* dstb = Bs[(r + 1) & 1];
            #pragma unroll
            for (int s = 0; s < 8; s++) {
                int cb = s * 256 + wave * 64;
                GLOAD_LDS16(src + (size_t)(cb + lane) * 8, &dstb[cb * 8]);
            }
        }

        // A fragments + row-sum state (on ti change)
        if (pti != curTi) {
            if (curTi >= 0) flushRow();
            const int iBase = pti * TILE;
            #pragma unroll
            for (int mt = 0; mt < 4; mt++) {
                const unsigned short* arow =
                    bf16x + (size_t)(iBase + wr + mt * 16 + lrow) * D;
                #pragma unroll
                for (int kk = 0; kk < 4; kk++)
                    af[mt][kk] = *(const short8*)&arow[((kk * 4 + quad) ^ lrow) * 8];
            }
            #pragma unroll
            for (int mt = 0; mt < 4; mt++)
                #pragma unroll
                for (int reg = 0; reg < 4; reg++) {
                    sie[mt][reg] = sq[iBase + wr + mt * 16 + quad * 4 + reg] * e2c;
                    rowAcc[mt][reg] = 0.f;
                }
            curTi = pti;
        }

        // ---- MFMA on current buffer ----
        const unsigned short* B = Bs[r & 1];
        floatx4 acc[4][4] = {};
        #pragma unroll
        for (int kk = 0; kk < 4; kk++) {
            short8 bfr[4];
            #pragma unroll
            for (int nt = 0; nt < 4; nt++) {
                int R = wc + nt * 16 + lrow;
                bfr[nt] = *(const short8*)&B[(size_t)R * D + ((kk * 4 + quad) ^ lrow) * 8];
            }
            #pragma unroll
            for (int mt = 0; mt < 4; mt++)
                #pragma unroll
                for (int nt = 0; nt < 4; nt++)
                    acc[mt][nt] = __builtin_amdgcn_mfma_f32_16x16x32_bf16(
                        af[mt][kk], bfr[nt], acc[mt][nt], 0, 0, 0);
        }

        // ---- epilogue: p = exp2(min((si+sj-2g)*c*log2e, 0)) ----
        // C/D layout: col = lane&15, row = quad*4 + reg  [learn_hip m89]
        float colAcc[4] = {0.f, 0.f, 0.f, 0.f};
        #pragma unroll
        for (int mt = 0; mt < 4; mt++) {
            #pragma unroll
            for (int reg = 0; reg < 4; reg++) {
                float base = sie[mt][reg];
                #pragma unroll
                for (int nt = 0; nt < 4; nt++) {
                    float p2 = fminf(fmaf(acc[mt][nt][reg], m2c, base + sje[nt]), 0.f);
                    float p = exp2f(p2);
                    rowAcc[mt][reg] += p;
                    colAcc[nt] += p;
                }
            }
        }

        // column sums -> rows of tj (strictly-upper pairs only)
        if (pti != ptj) {
            #pragma unroll
            for (int nt = 0; nt < 4; nt++) {
                float v = colAcc[nt];
                v += __shfl_xor(v, 16, 64);
                v += __shfl_xor(v, 32, 64);
                if (quad == 0)
                    atomicAdd(&rowsum[jBase + wc + nt * 16 + lrow], v);
            }
        }

        pti = nti; ptj = ntj;
        __syncthreads();  // drains prefetch DMA + guards buffer reuse
    }

    flushRow();
}

// k3: IXT = (ln N - mean_i ln rowsum[i]) / ln 2
__global__ __launch_bounds__(1024) void k3_final(
        const float* __restrict__ rowsum, float* __restrict__ out_ixt) {
    __shared__ float red[16];
    int t = threadIdx.x;
    float local = 0.f;
    for (int i = t; i < N; i += 1024) local += logf(rowsum[i]);
    #pragma unroll
    for (int m = 1; m < 64; m <<= 1) local += __shfl_xor(local, m, 64);
    if ((t & 63) == 0) red[t >> 6] = local;
    __syncthreads();
    if (t < 16) {
        float v = red[t];
        #pragma unroll
        for (int m = 1; m < 16; m <<= 1) v += __shfl_xor(v, m, 64);
        if (t == 0) {
            float kde = v / (float)N;
            out_ixt[0] = (logf((float)N) - kde) * 1.4426950408889634f;
        }
    }
}

// k4: out = x + var*noise (runs LAST — overwrites the bf16 scratch in d_out)
__global__ __launch_bounds__(256) void k4_noise(
        const float4* __restrict__ x, const float* __restrict__ phi,
        const float4* __restrict__ noise, float4* __restrict__ out) {
    int i = blockIdx.x * 256 + threadIdx.x;
    float var = softplus_of(phi);
    float4 xv = x[i], nv = noise[i];
    float4 ov;
    ov.x = xv.x + var * nv.x;
    ov.y = xv.y + var * nv.y;
    ov.z = xv.z + var * nv.z;
    ov.w = xv.w + var * nv.w;
    out[i] = ov;
}

extern "C" void kernel_launch(void* const* d_in, const int* in_sizes, int n_in,
                              void* d_out, int out_size, void* d_ws, size_t ws_size,
                              hipStream_t stream) {
    const float* x     = (const float*)d_in[0];
    const float* phi   = (const float*)d_in[1];
    const float* noise = (const float*)d_in[2];
    float* out = (float*)d_out;

    float* rowsum = (float*)d_ws;                 // N floats
    float* sq     = rowsum + N;                   // N floats
    unsigned short* bf16x = (unsigned short*)d_out;  // 2 MB scratch in d_out

    k1_cvt<<<(N * 16) / 256, 256, 0, stream>>>(x, bf16x, sq, rowsum);
    k2_gram<<<512, 256, 0, stream>>>(bf16x, phi, sq, rowsum);
    k3_final<<<1, 1024, 0, stream>>>(rowsum, out + (size_t)N * D);
    k4_noise<<<(N * D / 4) / 256, 256, 0, stream>>>(
        (const float4*)x, phi, (const float4*)noise, (float4*)out);
}